// Round 1
// baseline (177.036 us; speedup 1.0000x reference)
//
#include <hip/hip_runtime.h>

#define N 4096
#define NW (N / 16)          // 256 choice words per row
#define BLOCK 64
#define CHUNK 32             // floats per pipeline stage
#define NCHUNK (N / CHUNK)   // 128
#define QPC (CHUNK / 4)      // float4 loads per stage = 8

__global__ __launch_bounds__(BLOCK) void binarize_kernel(
    const float* __restrict__ probs, int* __restrict__ out) {
  const int tid = threadIdx.x;
  const long row = (long)blockIdx.x * BLOCK + tid;
  const float4* __restrict__ p4 = (const float4*)(probs + row * (long)N);
  int* __restrict__ orow = out + row * (long)N;

  // 2-bit choice codes, 16 steps per u32, lane-major: conflict-free (2-way aliasing is free)
  __shared__ unsigned cw_lds[NW][BLOCK];   // 64 KiB

  const int L = 512;
  int d = 0;   // d = f0 - f1 (renormalization-free state)

  float4 bufA[QPC], bufB[QPC];
#pragma unroll
  for (int q = 0; q < QPC; ++q) bufA[q] = p4[q];

  auto process = [&](const float4* buf, int c) {
#pragma unroll
    for (int h = 0; h < 2; ++h) {
      unsigned w = 0;
#pragma unroll
      for (int j = 0; j < 16; ++j) {
        float pv = ((const float*)buf)[h * 16 + j];
        int ai = (int)(1024.0f * pv);          // trunc == floor (pv >= 0)
        float q1 = 1.0f - pv;                  // separate op: no fma contraction
        int bi = (int)(1024.0f * q1);
        unsigned c0 = ((unsigned)(L - d)) >> 31;   // d >  L
        unsigned c1 = ((unsigned)(d + L)) >> 31;   // d < -L
        w |= (c0 << (2 * j)) | (c1 << (2 * j + 1));
        int dc = min(max(d, -L), L);               // v_med3_i32
        d = (ai - bi) + dc;
      }
      cw_lds[c * 2 + h][tid] = w;
    }
  };

  // software-pipelined forward: prefetch next 32-float stage while computing current
  for (int c = 0; c < NCHUNK; c += 2) {
#pragma unroll
    for (int q = 0; q < QPC; ++q) bufB[q] = p4[(c + 1) * QPC + q];
    process(bufA, c);
    if (c + 2 < NCHUNK) {
#pragma unroll
      for (int q = 0; q < QPC; ++q) bufA[q] = p4[(c + 2) * QPC + q];
    }
    process(bufB, c + 1);
  }

  // backtrack: x_i = c0(i+1) ? 1 : (c1(i+1) ? 0 : x_{i+1})  ==  (x | c0) & ~c1
  int x = (d >= 0) ? 1 : 0;   // x_last = (f1 <= f0)

  unsigned cw_hi;
  {
    unsigned cw = cw_lds[NW - 1][tid];
    int labs[16];
    labs[15] = x;
#pragma unroll
    for (int j = 14; j >= 0; --j) {
      unsigned b = cw >> (2 * (j + 1));
      x = (x | (int)(b & 1)) & (int)(((b >> 1) & 1) ^ 1);
      labs[j] = x;
    }
    int4* o4 = (int4*)(orow + (NW - 1) * 16);
    o4[0] = make_int4(labs[0], labs[1], labs[2], labs[3]);
    o4[1] = make_int4(labs[4], labs[5], labs[6], labs[7]);
    o4[2] = make_int4(labs[8], labs[9], labs[10], labs[11]);
    o4[3] = make_int4(labs[12], labs[13], labs[14], labs[15]);
    cw_hi = cw;
  }

  for (int wdx = NW - 2; wdx >= 0; --wdx) {
    unsigned cw = cw_lds[wdx][tid];
    int labs[16];
    {
      // j = 15 consumes bits 0,1 of the word above (position 16*(wdx+1))
      x = (x | (int)(cw_hi & 1)) & (int)(((cw_hi >> 1) & 1) ^ 1);
      labs[15] = x;
    }
#pragma unroll
    for (int j = 14; j >= 0; --j) {
      unsigned b = cw >> (2 * (j + 1));
      x = (x | (int)(b & 1)) & (int)(((b >> 1) & 1) ^ 1);
      labs[j] = x;
    }
    int4* o4 = (int4*)(orow + wdx * 16);
    o4[0] = make_int4(labs[0], labs[1], labs[2], labs[3]);
    o4[1] = make_int4(labs[4], labs[5], labs[6], labs[7]);
    o4[2] = make_int4(labs[8], labs[9], labs[10], labs[11]);
    o4[3] = make_int4(labs[12], labs[13], labs[14], labs[15]);
    cw_hi = cw;
  }
}

extern "C" void kernel_launch(void* const* d_in, const int* in_sizes, int n_in,
                              void* d_out, int out_size, void* d_ws, size_t ws_size,
                              hipStream_t stream) {
  const float* probs = (const float*)d_in[0];
  int* out = (int*)d_out;
  const int B = in_sizes[0] / N;        // 8192
  const int grid = B / BLOCK;           // 128 blocks x 64 threads = 1 thread/row
  binarize_kernel<<<grid, BLOCK, 0, stream>>>(probs, out);
}

// Round 2
// 75.737 us; speedup vs baseline: 2.3375x; 2.3375x over previous
//
#include <hip/hip_runtime.h>

#define N 4096
#define SEG 64            // elements per lane
#define BLOCK 64          // one wave per row
#define LCAP 512          // int(1024 * 0.5)
#define BIG (1 << 28)

__global__ __launch_bounds__(BLOCK) void binarize_kernel(
    const float* __restrict__ probs, int* __restrict__ out) {
  const int lane = threadIdx.x;
  const long row = blockIdx.x;
  const float4* __restrict__ p4 =
      (const float4*)(probs + row * (long)N + lane * SEG);
  int* __restrict__ orow = out + row * (long)N + lane * SEG;

  // ---- Phase 1: per-lane composed map (S,LO,HI) of d' = c + clamp(d,-L,L),
  //      while packing c = floor(1024p) - floor(1024(1-p)) as i16 pairs.
  int S = 0, lo = -BIG, hi = BIG;
  unsigned cp[SEG / 2];
#pragma unroll
  for (int q = 0; q < SEG / 4; ++q) {
    float4 v = p4[q];
    float pv[4] = {v.x, v.y, v.z, v.w};
#pragma unroll
    for (int e = 0; e < 2; ++e) {
      float pa = pv[2 * e], pb = pv[2 * e + 1];
      int a0 = (int)(1024.0f * pa);
      int b0 = (int)(1024.0f * (1.0f - pa));
      int a1 = (int)(1024.0f * pb);
      int b1 = (int)(1024.0f * (1.0f - pb));
      int ca = a0 - b0, cb = a1 - b1;
      cp[q * 2 + e] = ((unsigned)ca & 0xffffu) | ((unsigned)cb << 16);
      S += ca; lo = ca + min(max(lo, -LCAP), LCAP); hi = ca + min(max(hi, -LCAP), LCAP);
      S += cb; lo = cb + min(max(lo, -LCAP), LCAP); hi = cb + min(max(hi, -LCAP), LCAP);
    }
  }

  // ---- Phase 2: exclusive wave scan of maps -> exact incoming d per lane.
  int Sx = __shfl_up(S, 1), lox = __shfl_up(lo, 1), hix = __shfl_up(hi, 1);
  if (lane == 0) { Sx = 0; lox = -BIG; hix = BIG; }
#pragma unroll
  for (int dlt = 1; dlt < 64; dlt <<= 1) {
    int Si = __shfl_up(Sx, dlt);
    int loi = __shfl_up(lox, dlt);
    int hii = __shfl_up(hix, dlt);
    if (lane >= dlt) {
      int nlo = min(max(loi + Sx, lox), hix);   // incoming applied first
      int nhi = min(max(hii + Sx, lox), hix);
      Sx = Si + Sx;
      lox = nlo; hix = nhi;
    }
  }
  int d = min(max(Sx, lox), hix);  // h(0) = clamp(S, LO, HI)

  // ---- Phase 3: replay segment with exact d, record choice bits in 64-bit masks.
  unsigned m0lo = 0, m0hi = 0, m1lo = 0, m1hi = 0;
#pragma unroll
  for (int j = 0; j < SEG; ++j) {
    int c = (int)cp[j >> 1];
    c = (j & 1) ? (c >> 16) : ((c << 16) >> 16);        // sext i16
    unsigned b0 = ((unsigned)(LCAP - d)) >> 31;          // c0: d >  L
    unsigned b1 = ((unsigned)(d + LCAP)) >> 31;          // c1: d < -L
    if (j < 32) { m0lo |= b0 << j;        m1lo |= b1 << j; }
    else        { m0hi |= b0 << (j - 32); m1hi |= b1 << (j - 32); }
    d = c + min(max(d, -LCAP), LCAP);
  }

  // final label of the whole row
  int dfin = __shfl(d, 63);
  int xfin = (dfin >= 0) ? 1 : 0;

  // ---- Phase 4: per-lane backward composite P(x) = (x|S)&~R.
  // Leftmost (lowest j) force in the segment wins.
  unsigned long long M0 = ((unsigned long long)m0hi << 32) | m0lo;
  unsigned long long M1 = ((unsigned long long)m1hi << 32) | m1lo;
  unsigned long long Mm = M0 | M1;
  int Sb = 0, Rb = 0;
  int ffs = __ffsll((long long)Mm);       // 0 if no force
  if (ffs) {
    int j = ffs - 1;
    Sb = (int)((M0 >> j) & 1);
    Rb = (int)((M1 >> j) & 1);
  }
  int f = Sb | (Rb << 1);

  // reverse exclusive wave scan of latch functions (higher lane applied first)
  int fx = __shfl_down(f, 1);
  if (lane == 63) fx = 0;
#pragma unroll
  for (int dlt = 1; dlt < 64; dlt <<= 1) {
    int fi = __shfl_down(fx, dlt);
    if (lane < 64 - dlt) {
      int Sp = fi & 1, Rp = (fi >> 1) & 1;   // incoming (applied first)
      int Sq = fx & 1, Rq = (fx >> 1) & 1;   // own (applied last)
      int Sn = (Sp & (Rq ^ 1)) | Sq;
      int Rn = (Rp | Rq) & (Sn ^ 1);
      fx = Sn | (Rn << 1);
    }
  }
  // z = this lane's LAST label (segment-local j=63)
  int x = (xfin | (fx & 1)) & (((fx >> 1) & 1) ^ 1);

  // ---- Phase 5: in-segment backtrack + vectorized stores.
  int labv[4];
#pragma unroll
  for (int g = 15; g >= 0; --g) {
#pragma unroll
    for (int k = 3; k >= 0; --k) {
      int j = g * 4 + k;
      if (j == 63) { labv[k] = x; continue; }
      const int jp = j + 1;
      unsigned b0, b1;
      if (jp < 32) { b0 = (m0lo >> jp) & 1u; b1 = (m1lo >> jp) & 1u; }
      else         { b0 = (m0hi >> (jp - 32)) & 1u; b1 = (m1hi >> (jp - 32)) & 1u; }
      x = (x | (int)b0) & (int)(b1 ^ 1u);
      labv[k] = x;
    }
    ((int4*)orow)[g] = make_int4(labv[0], labv[1], labv[2], labv[3]);
  }
}

extern "C" void kernel_launch(void* const* d_in, const int* in_sizes, int n_in,
                              void* d_out, int out_size, void* d_ws, size_t ws_size,
                              hipStream_t stream) {
  const float* probs = (const float*)d_in[0];
  int* out = (int*)d_out;
  const int B = in_sizes[0] / N;   // 8192 rows
  binarize_kernel<<<B, BLOCK, 0, stream>>>(probs, out);
}